// Round 1
// baseline (546.483 us; speedup 1.0000x reference)
//
#include <hip/hip_runtime.h>
#include <hip/hip_bf16.h>
#include <stdint.h>

#define D_EMB 768
#define NHEADS 6
#define HD 128
#define BATCH 4
#define SEQ 2048
#define BH (BATCH*NHEADS)    // 24
#define M_ROWS (BATCH*SEQ)   // 8192

typedef float f32x4 __attribute__((ext_vector_type(4)));
typedef __bf16 bf16x8 __attribute__((ext_vector_type(8)));
typedef short short8 __attribute__((ext_vector_type(8)));

__device__ __forceinline__ short f2bf(float f) {
  union { float f; uint32_t u; } x; x.f = f;
  uint32_t r = x.u + 0x7fffu + ((x.u >> 16) & 1u);
  return (short)(r >> 16);
}

// ---------- x fp32 -> bf16 (vectorized) ----------
__global__ void cvt_f32_bf16_k(const float* __restrict__ in, short* __restrict__ out, int n4) {
  int i = blockIdx.x * 256 + threadIdx.x;
  if (i >= n4) return;
  float4 v = ((const float4*)in)[i];
  short4 o;
  o.x = f2bf(v.x); o.y = f2bf(v.y); o.z = f2bf(v.z); o.w = f2bf(v.w);
  ((short4*)out)[i] = o;
}

// ---------- W [R][C] fp32 -> WT [C][R] bf16 (tiled transpose) ----------
__global__ void transpose_w_k(const float* __restrict__ in, short* __restrict__ out, int R, int C) {
  __shared__ float tile[32][33];
  int c0 = blockIdx.x * 32, r0 = blockIdx.y * 32;
  int tx = threadIdx.x, ty = threadIdx.y;
  #pragma unroll
  for (int i = 0; i < 32; i += 8)
    tile[ty + i][tx] = in[(size_t)(r0 + ty + i) * C + (c0 + tx)];
  __syncthreads();
  #pragma unroll
  for (int i = 0; i < 32; i += 8)
    out[(size_t)(c0 + ty + i) * R + (r0 + tx)] = f2bf(tile[tx][ty + i]);
}

// ---------- V [bh][L][hd] bf16 -> Vt [bh][hd][L] bf16 ----------
__global__ void transpose_v_k(const short* __restrict__ in, short* __restrict__ out) {
  __shared__ short tile[32][33];
  const int hidx = blockIdx.z;
  const short* src = in + (size_t)hidx * SEQ * HD;
  short* dst = out + (size_t)hidx * SEQ * HD;
  int d0 = blockIdx.x * 32;
  int l0 = blockIdx.y * 32;
  int tx = threadIdx.x, ty = threadIdx.y;
  #pragma unroll
  for (int i = 0; i < 32; i += 8)
    tile[ty + i][tx] = src[(size_t)(l0 + ty + i) * HD + d0 + tx];
  __syncthreads();
  #pragma unroll
  for (int i = 0; i < 32; i += 8)
    dst[(size_t)(d0 + ty + i) * SEQ + l0 + tx] = tile[tx][ty + i];
}

// ---------- GEMM: C[M][N] = A[M][K] * BT[N][K]^T + bias ----------
// mode 0: fp32 out [M][N] (d_out)
// mode 1: bf16 out scattered to per-head layout [B][H][L][hd]
__global__ __launch_bounds__(256) void gemm_bt_k(
    const short* __restrict__ A, const short* __restrict__ BT,
    const float* __restrict__ bias,
    float* __restrict__ Cf, short* __restrict__ Cb,
    int M, int N, int K, int mode)
{
  __shared__ short Als[128][32];
  __shared__ short Bls[128][32];
  const int tid = threadIdx.x;
  const int lane = tid & 63;
  const int wave = tid >> 6;
  const int m0 = blockIdx.x * 128;
  const int n0 = blockIdx.y * 128;
  const int wm = (wave >> 1) * 64;
  const int wn = (wave & 1) * 64;
  const int lr = tid >> 2;         // 0..63
  const int lc = (tid & 3) * 8;    // 0,8,16,24
  const int frow = lane & 15;
  const int kk = (lane >> 4) * 8;
  f32x4 acc[4][4] = {};
  for (int k0 = 0; k0 < K; k0 += 32) {
    __syncthreads();
    *(short8*)&Als[lr][lc]      = *(const short8*)&A[(size_t)(m0 + lr) * K + k0 + lc];
    *(short8*)&Als[lr + 64][lc] = *(const short8*)&A[(size_t)(m0 + lr + 64) * K + k0 + lc];
    *(short8*)&Bls[lr][lc]      = *(const short8*)&BT[(size_t)(n0 + lr) * K + k0 + lc];
    *(short8*)&Bls[lr + 64][lc] = *(const short8*)&BT[(size_t)(n0 + lr + 64) * K + k0 + lc];
    __syncthreads();
    bf16x8 af[4], bfv[4];
    #pragma unroll
    for (int i = 0; i < 4; ++i) {
      af[i]  = *(const bf16x8*)&Als[wm + i * 16 + frow][kk];
      bfv[i] = *(const bf16x8*)&Bls[wn + i * 16 + frow][kk];
    }
    #pragma unroll
    for (int i = 0; i < 4; ++i)
      #pragma unroll
      for (int j = 0; j < 4; ++j)
        acc[i][j] = __builtin_amdgcn_mfma_f32_16x16x32_bf16(af[i], bfv[j], acc[i][j], 0, 0, 0);
  }
  const int r0l = (lane >> 4) * 4;
  const int cl = lane & 15;
  #pragma unroll
  for (int i = 0; i < 4; ++i) {
    #pragma unroll
    for (int j = 0; j < 4; ++j) {
      int col = n0 + wn + j * 16 + cl;
      float bv = bias ? bias[col] : 0.f;
      #pragma unroll
      for (int r = 0; r < 4; ++r) {
        int m = m0 + wm + i * 16 + r0l + r;
        float v = acc[i][j][r] + bv;
        if (mode == 0) {
          Cf[(size_t)m * N + col] = v;
        } else {
          int b = m >> 11, li = m & 2047;
          int h = col >> 7, d = col & 127;
          Cb[((((size_t)b * NHEADS + h) << 11) + li) * HD + d] = f2bf(v);
        }
      }
    }
  }
}

// ---------- causal flash attention, 1 wave / 16 q-rows ----------
// Q,K: [bh][L][hd] bf16 ; Vt: [bh][hd][L] bf16 ; O: [B][L][D] bf16
__global__ __launch_bounds__(64) void attn_causal_k(
    const short* __restrict__ Q, const short* __restrict__ K,
    const short* __restrict__ Vt, short* __restrict__ O)
{
  __shared__ short Pls[16][32];
  const int lane = threadIdx.x;
  const int qt = blockIdx.x;
  const int bh = blockIdx.y;
  const short* Qh = Q + (size_t)bh * SEQ * HD;
  const short* Kh = K + (size_t)bh * SEQ * HD;
  const short* Vh = Vt + (size_t)bh * SEQ * HD;  // [HD][SEQ]
  const int q0 = qt * 16;
  const int g = lane >> 4;       // 0..3
  const int cl = lane & 15;      // 0..15
  bf16x8 qf[4];
  #pragma unroll
  for (int c = 0; c < 4; ++c)
    qf[c] = *(const bf16x8*)&Qh[(size_t)(q0 + cl) * HD + c * 32 + g * 8];
  f32x4 o[8] = {};
  float mrow[4] = {-1e30f, -1e30f, -1e30f, -1e30f};
  float lrow[4] = {0.f, 0.f, 0.f, 0.f};
  const float scale = 0.08838834764831845f;  // 1/sqrt(128)
  const int jmax = q0 + 15;
  for (int j0 = 0; j0 <= jmax; j0 += 32) {
    f32x4 s0 = {}, s1 = {};
    #pragma unroll
    for (int c = 0; c < 4; ++c) {
      bf16x8 kf0 = *(const bf16x8*)&Kh[(size_t)(j0 + cl) * HD + c * 32 + g * 8];
      bf16x8 kf1 = *(const bf16x8*)&Kh[(size_t)(j0 + 16 + cl) * HD + c * 32 + g * 8];
      s0 = __builtin_amdgcn_mfma_f32_16x16x32_bf16(qf[c], kf0, s0, 0, 0, 0);
      s1 = __builtin_amdgcn_mfma_f32_16x16x32_bf16(qf[c], kf1, s1, 0, 0, 0);
    }
    #pragma unroll
    for (int r = 0; r < 4; ++r) {
      const int qi = q0 + g * 4 + r;
      float v0 = s0[r] * scale; if (j0 + cl > qi) v0 = -1e30f;
      float v1 = s1[r] * scale; if (j0 + 16 + cl > qi) v1 = -1e30f;
      float mx = fmaxf(v0, v1);
      #pragma unroll
      for (int off = 1; off < 16; off <<= 1)
        mx = fmaxf(mx, __shfl_xor(mx, off, 64));
      const float mnew = fmaxf(mrow[r], mx);
      const float corr = __expf(mrow[r] - mnew);
      const float p0 = __expf(v0 - mnew);
      const float p1 = __expf(v1 - mnew);
      float ps = p0 + p1;
      #pragma unroll
      for (int off = 1; off < 16; off <<= 1)
        ps += __shfl_xor(ps, off, 64);
      lrow[r] = lrow[r] * corr + ps;
      mrow[r] = mnew;
      #pragma unroll
      for (int f = 0; f < 8; ++f) o[f][r] *= corr;
      Pls[g * 4 + r][cl] = f2bf(p0);
      Pls[g * 4 + r][cl + 16] = f2bf(p1);
    }
    __syncthreads();
    const bf16x8 pf = *(const bf16x8*)&Pls[cl][g * 8];
    #pragma unroll
    for (int f = 0; f < 8; ++f) {
      bf16x8 vf = *(const bf16x8*)&Vh[(size_t)(f * 16 + cl) * SEQ + j0 + g * 8];
      o[f] = __builtin_amdgcn_mfma_f32_16x16x32_bf16(pf, vf, o[f], 0, 0, 0);
    }
    __syncthreads();
  }
  const int b = bh / NHEADS, h = bh % NHEADS;
  #pragma unroll
  for (int r = 0; r < 4; ++r) {
    const int qi = q0 + g * 4 + r;
    const float invl = 1.0f / lrow[r];
    size_t base = ((size_t)b * SEQ + qi) * D_EMB + h * HD;
    #pragma unroll
    for (int f = 0; f < 8; ++f)
      O[base + f * 16 + cl] = f2bf(o[f][r] * invl);
  }
}

extern "C" void kernel_launch(void* const* d_in, const int* in_sizes, int n_in,
                              void* d_out, int out_size, void* d_ws, size_t ws_size,
                              hipStream_t stream) {
  const float* x  = (const float*)d_in[0];
  const float* Wq = (const float*)d_in[1];
  const float* bq = (const float*)d_in[2];
  const float* Wk = (const float*)d_in[3];
  const float* bk = (const float*)d_in[4];
  const float* Wv = (const float*)d_in[5];
  const float* bv = (const float*)d_in[6];
  const float* Wo = (const float*)d_in[7];
  const float* bo = (const float*)d_in[8];
  float* out = (float*)d_out;

  char* ws = (char*)d_ws;
  size_t off = 0;
  auto carve = [&](size_t bytes) {
    char* p = ws + off;
    off += (bytes + 255) & ~(size_t)255;
    return p;
  };
  short* xb  = (short*)carve((size_t)M_ROWS * D_EMB * 2);
  short* wqt = (short*)carve((size_t)D_EMB * D_EMB * 2);
  short* wkt = (short*)carve((size_t)D_EMB * D_EMB * 2);
  short* wvt = (short*)carve((size_t)D_EMB * D_EMB * 2);
  short* wot = (short*)carve((size_t)D_EMB * D_EMB * 2);
  short* Qb  = (short*)carve((size_t)BH * SEQ * HD * 2);
  short* Kb  = (short*)carve((size_t)BH * SEQ * HD * 2);
  short* Vb  = (short*)carve((size_t)BH * SEQ * HD * 2);
  short* Vtb = (short*)carve((size_t)BH * SEQ * HD * 2);
  short* Ob  = (short*)carve((size_t)M_ROWS * D_EMB * 2);

  int n4 = M_ROWS * D_EMB / 4;
  cvt_f32_bf16_k<<<(n4 + 255) / 256, 256, 0, stream>>>(x, xb, n4);

  dim3 tb(32, 8);
  transpose_w_k<<<dim3(24, 24), tb, 0, stream>>>(Wq, wqt, D_EMB, D_EMB);
  transpose_w_k<<<dim3(24, 24), tb, 0, stream>>>(Wk, wkt, D_EMB, D_EMB);
  transpose_w_k<<<dim3(24, 24), tb, 0, stream>>>(Wv, wvt, D_EMB, D_EMB);
  transpose_w_k<<<dim3(24, 24), tb, 0, stream>>>(Wo, wot, D_EMB, D_EMB);

  dim3 gg(M_ROWS / 128, D_EMB / 128);
  gemm_bt_k<<<gg, 256, 0, stream>>>(xb, wqt, bq, nullptr, Qb, M_ROWS, D_EMB, D_EMB, 1);
  gemm_bt_k<<<gg, 256, 0, stream>>>(xb, wkt, bk, nullptr, Kb, M_ROWS, D_EMB, D_EMB, 1);
  gemm_bt_k<<<gg, 256, 0, stream>>>(xb, wvt, bv, nullptr, Vb, M_ROWS, D_EMB, D_EMB, 1);

  transpose_v_k<<<dim3(HD / 32, SEQ / 32, BH), tb, 0, stream>>>(Vb, Vtb);

  attn_causal_k<<<dim3(SEQ / 16, BH), 64, 0, stream>>>(Qb, Kb, Vtb, Ob);

  gemm_bt_k<<<gg, 256, 0, stream>>>(Ob, wot, bo, out, nullptr, M_ROWS, D_EMB, D_EMB, 0);
}

// Round 2
// 474.598 us; speedup vs baseline: 1.1515x; 1.1515x over previous
//
#include <hip/hip_runtime.h>
#include <hip/hip_bf16.h>
#include <stdint.h>

#define D_EMB 768
#define NHEADS 6
#define HD 128
#define BATCH 4
#define SEQ 2048
#define BH (BATCH*NHEADS)    // 24
#define M_ROWS (BATCH*SEQ)   // 8192

typedef float f32x4 __attribute__((ext_vector_type(4)));
typedef __bf16 bf16x8 __attribute__((ext_vector_type(8)));
typedef short short8 __attribute__((ext_vector_type(8)));

__device__ __forceinline__ short f2bf(float f) {
  union { float f; uint32_t u; } x; x.f = f;
  uint32_t r = x.u + 0x7fffu + ((x.u >> 16) & 1u);
  return (short)(r >> 16);
}

__device__ __forceinline__ void gload16(const void* g, void* l) {
  __builtin_amdgcn_global_load_lds(
      (const __attribute__((address_space(1))) unsigned int*)g,
      (__attribute__((address_space(3))) unsigned int*)l, 16, 0, 0);
}

// ---------- x fp32 -> bf16 (vectorized) ----------
__global__ void cvt_f32_bf16_k(const float* __restrict__ in, short* __restrict__ out, int n4) {
  int i = blockIdx.x * 256 + threadIdx.x;
  if (i >= n4) return;
  float4 v = ((const float4*)in)[i];
  short4 o;
  o.x = f2bf(v.x); o.y = f2bf(v.y); o.z = f2bf(v.z); o.w = f2bf(v.w);
  ((short4*)out)[i] = o;
}

// ---------- W [R][C] fp32 -> WT [C][R] bf16 (tiled transpose) ----------
__global__ void transpose_w_k(const float* __restrict__ in, short* __restrict__ out, int R, int C) {
  __shared__ float tile[32][33];
  int c0 = blockIdx.x * 32, r0 = blockIdx.y * 32;
  int tx = threadIdx.x, ty = threadIdx.y;
  #pragma unroll
  for (int i = 0; i < 32; i += 8)
    tile[ty + i][tx] = in[(size_t)(r0 + ty + i) * C + (c0 + tx)];
  __syncthreads();
  #pragma unroll
  for (int i = 0; i < 32; i += 8)
    out[(size_t)(c0 + ty + i) * R + (r0 + tx)] = f2bf(tile[tx][ty + i]);
}

// ---------- V [bh][L][hd] bf16 -> Vt [bh][hd][L] bf16 ----------
__global__ void transpose_v_k(const short* __restrict__ in, short* __restrict__ out) {
  __shared__ short tile[32][33];
  const int hidx = blockIdx.z;
  const short* src = in + (size_t)hidx * SEQ * HD;
  short* dst = out + (size_t)hidx * SEQ * HD;
  int d0 = blockIdx.x * 32;
  int l0 = blockIdx.y * 32;
  int tx = threadIdx.x, ty = threadIdx.y;
  #pragma unroll
  for (int i = 0; i < 32; i += 8)
    tile[ty + i][tx] = src[(size_t)(l0 + ty + i) * HD + d0 + tx];
  __syncthreads();
  #pragma unroll
  for (int i = 0; i < 32; i += 8)
    dst[(size_t)(d0 + ty + i) * SEQ + l0 + tx] = tile[tx][ty + i];
}

// ---------- GEMM: C[M][N] = A[M][K] * BT[N][K]^T + bias ----------
// global_load_lds staging (m97 pattern). mode 0: fp32 out. mode 1: bf16 per-head layout.
__global__ __launch_bounds__(256) void gemm_bt_k(
    const short* __restrict__ A, const short* __restrict__ BT,
    const float* __restrict__ bias,
    float* __restrict__ Cf, short* __restrict__ Cb,
    int M, int N, int K, int mode)
{
  __shared__ short Als[128][32];
  __shared__ short Bls[128][32];
  const int tid = threadIdx.x;
  const int lane = tid & 63;
  const int wave = tid >> 6;
  const int m0 = blockIdx.x * 128;
  const int n0 = blockIdx.y * 128;
  const int wm = (wave >> 1) * 64;
  const int wn = (wave & 1) * 64;
  const int lr = tid >> 2;         // row 0..63
  const int lc = (tid & 3) * 8;    // 0,8,16,24
  const int frow = lane & 15;
  const int kk = (lane >> 4) * 8;
  f32x4 acc[4][4] = {};
  for (int k0 = 0; k0 < K; k0 += 32) {
    __syncthreads();
    // LDS byte layout is linear in tid*16 -> global_load_lds drop-in
    gload16(&A[(size_t)(m0 + lr) * K + k0 + lc],       (char*)Als + wave * 1024);
    gload16(&A[(size_t)(m0 + lr + 64) * K + k0 + lc],  (char*)Als + 4096 + wave * 1024);
    gload16(&BT[(size_t)(n0 + lr) * K + k0 + lc],      (char*)Bls + wave * 1024);
    gload16(&BT[(size_t)(n0 + lr + 64) * K + k0 + lc], (char*)Bls + 4096 + wave * 1024);
    __syncthreads();  // drains vmcnt(0) for global_load_lds
    bf16x8 af[4], bfv[4];
    #pragma unroll
    for (int i = 0; i < 4; ++i) {
      af[i]  = *(const bf16x8*)&Als[wm + i * 16 + frow][kk];
      bfv[i] = *(const bf16x8*)&Bls[wn + i * 16 + frow][kk];
    }
    #pragma unroll
    for (int i = 0; i < 4; ++i)
      #pragma unroll
      for (int j = 0; j < 4; ++j)
        acc[i][j] = __builtin_amdgcn_mfma_f32_16x16x32_bf16(af[i], bfv[j], acc[i][j], 0, 0, 0);
  }
  const int r0l = (lane >> 4) * 4;
  const int cl = lane & 15;
  #pragma unroll
  for (int i = 0; i < 4; ++i) {
    #pragma unroll
    for (int j = 0; j < 4; ++j) {
      int col = n0 + wn + j * 16 + cl;
      float bv = bias ? bias[col] : 0.f;
      #pragma unroll
      for (int r = 0; r < 4; ++r) {
        int m = m0 + wm + i * 16 + r0l + r;
        float v = acc[i][j][r] + bv;
        if (mode == 0) {
          Cf[(size_t)m * N + col] = v;
        } else {
          int b = m >> 11, li = m & 2047;
          int h = col >> 7, d = col & 127;
          Cb[((((size_t)b * NHEADS + h) << 11) + li) * HD + d] = f2bf(v);
        }
      }
    }
  }
}

// ---------- causal flash attention v2 ----------
// 256 threads = 4 waves; block owns 128 q-rows (wave: 2 m-frags of 16).
// KVBLK=64. K LDS [64][128], Vt LDS [128][64], both XOR-swizzled via
// pre-swizzled global_load_lds source. P per-wave LDS, swizzled.
__global__ __launch_bounds__(256) void attn_causal_k(
    const short* __restrict__ Q, const short* __restrict__ K,
    const short* __restrict__ Vt, short* __restrict__ O)
{
  __shared__ short Kls[64 * 128];
  __shared__ short Vls[128 * 64];
  __shared__ short Pls[4][32 * 64];

  const int tid = threadIdx.x;
  const int lane = tid & 63;
  const int wave = tid >> 6;
  const int g = lane >> 4;       // 0..3
  const int cl = lane & 15;      // 0..15
  const int bh = blockIdx.y;
  const int qb0 = (SEQ / 128 - 1 - (int)blockIdx.x) * 128;  // longest blocks first
  const int qw0 = qb0 + wave * 32;

  const short* Qh = Q + (size_t)bh * SEQ * HD;
  const short* Kh = K + (size_t)bh * SEQ * HD;
  const short* Vh = Vt + (size_t)bh * SEQ * HD;  // [HD][SEQ]

  bf16x8 qf[2][4];
  #pragma unroll
  for (int m = 0; m < 2; ++m)
    #pragma unroll
    for (int c = 0; c < 4; ++c)
      qf[m][c] = *(const bf16x8*)&Qh[(size_t)(qw0 + m * 16 + cl) * HD + c * 32 + g * 8];

  f32x4 o[2][8] = {};
  float mrow[2][4], lrow[2][4];
  #pragma unroll
  for (int m = 0; m < 2; ++m)
    #pragma unroll
    for (int r = 0; r < 4; ++r) { mrow[m][r] = -1e30f; lrow[m][r] = 0.f; }

  const float kSc = 0.08838834764831845f * 1.44269504088896341f;  // 1/sqrt(128)*log2(e)
  const int swzr = (cl & 7) << 4;  // read-side swizzle (row&7 == cl&7 for all our reads)

  for (int j0 = 0; j0 < qb0 + 128; j0 += 64) {
    __syncthreads();  // prev tile's LDS reads complete before overwrite
    // stage K tile [64][128]: linear LDS dest, inverse-swizzled global src
    #pragma unroll
    for (int t = 0; t < 4; ++t) {
      int row = wave * 16 + t * 4 + g;
      int cb = (cl * 16) ^ ((row & 7) << 4);
      gload16((const char*)Kh + ((size_t)(j0 + row) * HD) * 2 + cb,
              (char*)Kls + (wave * 4 + t) * 1024);
    }
    // stage Vt tile [128][64]
    #pragma unroll
    for (int t = 0; t < 4; ++t) {
      int row = wave * 32 + t * 8 + (lane >> 3);
      int cb = ((lane & 7) * 16) ^ ((row & 7) << 4);
      gload16((const char*)Vh + ((size_t)row * SEQ + j0) * 2 + cb,
              (char*)Vls + (wave * 4 + t) * 1024);
    }
    __syncthreads();  // vmcnt(0): tiles ready

    if (j0 <= qw0 + 31) {
      // ---- QK^T: s[m][jf] = Q[m] * K[jf]^T
      f32x4 s[2][4] = {};
      #pragma unroll
      for (int jf = 0; jf < 4; ++jf) {
        bf16x8 kf[4];
        #pragma unroll
        for (int c = 0; c < 4; ++c)
          kf[c] = *(const bf16x8*)((const char*)Kls + (jf * 16 + cl) * 256 +
                                   ((c * 64 + g * 16) ^ swzr));
        #pragma unroll
        for (int m = 0; m < 2; ++m)
          #pragma unroll
          for (int c = 0; c < 4; ++c)
            s[m][jf] = __builtin_amdgcn_mfma_f32_16x16x32_bf16(qf[m][c], kf[c], s[m][jf], 0, 0, 0);
      }
      // ---- online softmax (exp2 domain) + P -> LDS (bf16, swizzled)
      char* Pw = (char*)&Pls[wave][0];
      #pragma unroll
      for (int m = 0; m < 2; ++m) {
        #pragma unroll
        for (int r = 0; r < 4; ++r) {
          const int qi = qw0 + m * 16 + g * 4 + r;
          float v[4];
          float mx = -1e30f;
          #pragma unroll
          for (int jf = 0; jf < 4; ++jf) {
            float x = s[m][jf][r] * kSc;
            if (j0 + jf * 16 + cl > qi) x = -1e30f;
            v[jf] = x;
            mx = fmaxf(mx, x);
          }
          #pragma unroll
          for (int off2 = 1; off2 < 16; off2 <<= 1)
            mx = fmaxf(mx, __shfl_xor(mx, off2));
          const float mnew = fmaxf(mrow[m][r], mx);
          const float corr = __builtin_amdgcn_exp2f(mrow[m][r] - mnew);
          mrow[m][r] = mnew;
          const int rl = m * 16 + g * 4 + r;
          const int swzw = (rl & 7) << 4;
          float ps = 0.f;
          #pragma unroll
          for (int jf = 0; jf < 4; ++jf) {
            float p = __builtin_amdgcn_exp2f(v[jf] - mnew);
            ps += p;
            *(short*)(Pw + rl * 128 + (((jf * 16 + cl) * 2) ^ swzw)) = f2bf(p);
          }
          #pragma unroll
          for (int off2 = 1; off2 < 16; off2 <<= 1)
            ps += __shfl_xor(ps, off2);
          lrow[m][r] = lrow[m][r] * corr + ps;
          #pragma unroll
          for (int f = 0; f < 8; ++f) o[m][f][r] *= corr;
        }
      }
      asm volatile("s_waitcnt lgkmcnt(0)" ::: "memory");  // P writes visible to wave
      // ---- PV: o[m] += P[m] * V
      #pragma unroll
      for (int ks = 0; ks < 2; ++ks) {
        bf16x8 pf[2];
        #pragma unroll
        for (int m = 0; m < 2; ++m)
          pf[m] = *(const bf16x8*)(Pw + (m * 16 + cl) * 128 + ((ks * 64 + g * 16) ^ swzr));
        #pragma unroll
        for (int f = 0; f < 8; ++f) {
          bf16x8 vf = *(const bf16x8*)((const char*)Vls + (f * 16 + cl) * 128 +
                                       ((ks * 64 + g * 16) ^ swzr));
          #pragma unroll
          for (int m = 0; m < 2; ++m)
            o[m][f] = __builtin_amdgcn_mfma_f32_16x16x32_bf16(pf[m], vf, o[m][f], 0, 0, 0);
        }
      }
    }
  }

  const int b = bh / NHEADS, h = bh % NHEADS;
  #pragma unroll
  for (int m = 0; m < 2; ++m) {
    #pragma unroll
    for (int r = 0; r < 4; ++r) {
      const int qi = qw0 + m * 16 + g * 4 + r;
      const float invl = 1.0f / lrow[m][r];
      size_t base = ((size_t)b * SEQ + qi) * D_EMB + h * HD;
      #pragma unroll
      for (int f = 0; f < 8; ++f)
        O[base + f * 16 + cl] = f2bf(o[m][f][r] * invl);
    }
  }
}

extern "C" void kernel_launch(void* const* d_in, const int* in_sizes, int n_in,
                              void* d_out, int out_size, void* d_ws, size_t ws_size,
                              hipStream_t stream) {
  const float* x  = (const float*)d_in[0];
  const float* Wq = (const float*)d_in[1];
  const float* bq = (const float*)d_in[2];
  const float* Wk = (const float*)d_in[3];
  const float* bk = (const float*)d_in[4];
  const float* Wv = (const float*)d_in[5];
  const float* bv = (const float*)d_in[6];
  const float* Wo = (const float*)d_in[7];
  const float* bo = (const float*)d_in[8];
  float* out = (float*)d_out;

  char* ws = (char*)d_ws;
  size_t off = 0;
  auto carve = [&](size_t bytes) {
    char* p = ws + off;
    off += (bytes + 255) & ~(size_t)255;
    return p;
  };
  short* xb  = (short*)carve((size_t)M_ROWS * D_EMB * 2);
  short* wqt = (short*)carve((size_t)D_EMB * D_EMB * 2);
  short* wkt = (short*)carve((size_t)D_EMB * D_EMB * 2);
  short* wvt = (short*)carve((size_t)D_EMB * D_EMB * 2);
  short* wot = (short*)carve((size_t)D_EMB * D_EMB * 2);
  short* Qb  = (short*)carve((size_t)BH * SEQ * HD * 2);
  short* Kb  = (short*)carve((size_t)BH * SEQ * HD * 2);
  short* Vb  = (short*)carve((size_t)BH * SEQ * HD * 2);
  short* Vtb = (short*)carve((size_t)BH * SEQ * HD * 2);
  short* Ob  = (short*)carve((size_t)M_ROWS * D_EMB * 2);

  int n4 = M_ROWS * D_EMB / 4;
  cvt_f32_bf16_k<<<(n4 + 255) / 256, 256, 0, stream>>>(x, xb, n4);

  dim3 tb(32, 8);
  transpose_w_k<<<dim3(24, 24), tb, 0, stream>>>(Wq, wqt, D_EMB, D_EMB);
  transpose_w_k<<<dim3(24, 24), tb, 0, stream>>>(Wk, wkt, D_EMB, D_EMB);
  transpose_w_k<<<dim3(24, 24), tb, 0, stream>>>(Wv, wvt, D_EMB, D_EMB);
  transpose_w_k<<<dim3(24, 24), tb, 0, stream>>>(Wo, wot, D_EMB, D_EMB);

  dim3 gg(M_ROWS / 128, D_EMB / 128);
  gemm_bt_k<<<gg, 256, 0, stream>>>(xb, wqt, bq, nullptr, Qb, M_ROWS, D_EMB, D_EMB, 1);
  gemm_bt_k<<<gg, 256, 0, stream>>>(xb, wkt, bk, nullptr, Kb, M_ROWS, D_EMB, D_EMB, 1);
  gemm_bt_k<<<gg, 256, 0, stream>>>(xb, wvt, bv, nullptr, Vb, M_ROWS, D_EMB, D_EMB, 1);

  transpose_v_k<<<dim3(HD / 32, SEQ / 32, BH), tb, 0, stream>>>(Vb, Vtb);

  attn_causal_k<<<dim3(SEQ / 128, BH), 256, 0, stream>>>(Qb, Kb, Vtb, Ob);

  gemm_bt_k<<<gg, 256, 0, stream>>>(Ob, wot, bo, out, nullptr, M_ROWS, D_EMB, D_EMB, 0);
}

// Round 4
// 450.767 us; speedup vs baseline: 1.2123x; 1.0529x over previous
//
#include <hip/hip_runtime.h>
#include <hip/hip_bf16.h>
#include <stdint.h>

#define D_EMB 768
#define NHEADS 6
#define HD 128
#define BATCH 4
#define SEQ 2048
#define BH (BATCH*NHEADS)    // 24
#define M_ROWS (BATCH*SEQ)   // 8192

typedef float f32x4 __attribute__((ext_vector_type(4)));
typedef __bf16 bf16x8 __attribute__((ext_vector_type(8)));
typedef short short8 __attribute__((ext_vector_type(8)));

__device__ __forceinline__ short f2bf(float f) {
  union { float f; uint32_t u; } x; x.f = f;
  uint32_t r = x.u + 0x7fffu + ((x.u >> 16) & 1u);
  return (short)(r >> 16);
}

__device__ __forceinline__ void gload16(const void* g, void* l) {
  __builtin_amdgcn_global_load_lds(
      (const __attribute__((address_space(1))) unsigned int*)g,
      (__attribute__((address_space(3))) unsigned int*)l, 16, 0, 0);
}

// ---------- x fp32 -> bf16 (vectorized) ----------
__global__ void cvt_f32_bf16_k(const float* __restrict__ in, short* __restrict__ out, int n4) {
  int i = blockIdx.x * 256 + threadIdx.x;
  if (i >= n4) return;
  float4 v = ((const float4*)in)[i];
  short4 o;
  o.x = f2bf(v.x); o.y = f2bf(v.y); o.z = f2bf(v.z); o.w = f2bf(v.w);
  ((short4*)out)[i] = o;
}

// ---------- W [R][C] fp32 -> WT [C][R] bf16 (tiled transpose) ----------
__global__ void transpose_w_k(const float* __restrict__ in, short* __restrict__ out, int R, int C) {
  __shared__ float tile[32][33];
  int c0 = blockIdx.x * 32, r0 = blockIdx.y * 32;
  int tx = threadIdx.x, ty = threadIdx.y;
  #pragma unroll
  for (int i = 0; i < 32; i += 8)
    tile[ty + i][tx] = in[(size_t)(r0 + ty + i) * C + (c0 + tx)];
  __syncthreads();
  #pragma unroll
  for (int i = 0; i < 32; i += 8)
    out[(size_t)(c0 + ty + i) * R + (r0 + tx)] = f2bf(tile[tx][ty + i]);
}

// ---------- V [bh][L][hd] bf16 -> Vt [bh][hd][L] bf16 ----------
__global__ void transpose_v_k(const short* __restrict__ in, short* __restrict__ out) {
  __shared__ short tile[32][33];
  const int hidx = blockIdx.z;
  const short* src = in + (size_t)hidx * SEQ * HD;
  short* dst = out + (size_t)hidx * SEQ * HD;
  int d0 = blockIdx.x * 32;
  int l0 = blockIdx.y * 32;
  int tx = threadIdx.x, ty = threadIdx.y;
  #pragma unroll
  for (int i = 0; i < 32; i += 8)
    tile[ty + i][tx] = src[(size_t)(l0 + ty + i) * HD + d0 + tx];
  __syncthreads();
  #pragma unroll
  for (int i = 0; i < 32; i += 8)
    dst[(size_t)(d0 + ty + i) * SEQ + l0 + tx] = tile[tx][ty + i];
}

// ---------- GEMM: C[M][N] = A[M][K] * BT[N][K]^T + bias ----------
// BM=128, BN=64, double-buffered global_load_lds, 1 barrier / k-step.
// mode 0: fp32 out [M][N]. mode 1: bf16 out scattered to [B][H][L][hd].
__global__ __launch_bounds__(256) void gemm_bt_k(
    const short* __restrict__ A, const short* __restrict__ BT,
    const float* __restrict__ bias,
    float* __restrict__ Cf, short* __restrict__ Cb,
    int M, int N, int K, int mode)
{
  __shared__ short Als[2][128][32];  // 2 x 8KB
  __shared__ short Bls[2][64][32];   // 2 x 4KB
  const int tid = threadIdx.x;
  const int lane = tid & 63;
  const int wave = tid >> 6;
  const int m0 = blockIdx.x * 128;
  const int n0 = blockIdx.y * 64;
  const int wm = (wave & 1) * 64;
  const int wn = (wave >> 1) * 32;
  const int lr = tid >> 2;         // row 0..63
  const int lc = (tid & 3) * 8;    // k-offset in elements (16B chunks)
  const int frow = lane & 15;
  const int kk = (lane >> 4) * 8;

  #define G_STAGE(buf, k0)                                                      \
    do {                                                                        \
      gload16(&A[(size_t)(m0 + lr) * K + (k0) + lc],                            \
              (char*)Als[buf] + wave * 1024);                                   \
      gload16(&A[(size_t)(m0 + lr + 64) * K + (k0) + lc],                       \
              (char*)Als[buf] + 4096 + wave * 1024);                            \
      gload16(&BT[(size_t)(n0 + lr) * K + (k0) + lc],                           \
              (char*)Bls[buf] + wave * 1024);                                   \
    } while (0)

  f32x4 acc[4][2] = {};
  G_STAGE(0, 0);
  __syncthreads();
  int buf = 0;
  for (int k0 = 0; k0 < K; k0 += 32) {
    if (k0 + 32 < K) G_STAGE(buf ^ 1, k0 + 32);
    bf16x8 af[4], bfv[2];
    #pragma unroll
    for (int i = 0; i < 4; ++i)
      af[i] = *(const bf16x8*)&Als[buf][wm + i * 16 + frow][kk];
    #pragma unroll
    for (int j = 0; j < 2; ++j)
      bfv[j] = *(const bf16x8*)&Bls[buf][wn + j * 16 + frow][kk];
    #pragma unroll
    for (int i = 0; i < 4; ++i)
      #pragma unroll
      for (int j = 0; j < 2; ++j)
        acc[i][j] = __builtin_amdgcn_mfma_f32_16x16x32_bf16(af[i], bfv[j], acc[i][j], 0, 0, 0);
    __syncthreads();  // drains vmcnt+lgkm: next buffer staged, this buffer free
    buf ^= 1;
  }
  #undef G_STAGE

  const int r0l = (lane >> 4) * 4;
  const int cl = lane & 15;
  #pragma unroll
  for (int i = 0; i < 4; ++i) {
    #pragma unroll
    for (int j = 0; j < 2; ++j) {
      int col = n0 + wn + j * 16 + cl;
      float bv = bias ? bias[col] : 0.f;
      #pragma unroll
      for (int r = 0; r < 4; ++r) {
        int m = m0 + wm + i * 16 + r0l + r;
        float v = acc[i][j][r] + bv;
        if (mode == 0) {
          Cf[(size_t)m * N + col] = v;
        } else {
          int b = m >> 11, li = m & 2047;
          int h = col >> 7, d = col & 127;
          Cb[((((size_t)b * NHEADS + h) << 11) + li) * HD + d] = f2bf(v);
        }
      }
    }
  }
}

// ---------- causal flash attention v3: barrier-free independent waves ----------
// 4 waves/block, each wave owns 32 q-rows and scans its own causal kv-range.
// K/V read directly from global (L2-resident per head); P per-wave swizzled LDS.
// Grid: 384 blocks, XCD-chunk swizzled (48 blocks = 3 heads per XCD).
__global__ __launch_bounds__(256) void attn_causal_k(
    const short* __restrict__ Q, const short* __restrict__ K,
    const short* __restrict__ Vt, short* __restrict__ O)
{
  __shared__ short Pls[4][32 * 64];  // 4KB per wave

  const int tid = threadIdx.x;
  const int lane = tid & 63;
  const int wave = tid >> 6;
  const int g = lane >> 4;       // 0..3
  const int cl = lane & 15;      // 0..15

  // XCD-chunk swizzle: 384 blocks / 8 XCDs = 48 per XCD = 3 whole heads
  const int bid = (int)blockIdx.x;
  const int sid = (bid & 7) * 48 + (bid >> 3);
  const int bh = sid >> 4;
  const int tsuper = sid & 15;
  const int qt = 63 - (tsuper * 4 + wave);   // 32-row tile idx, longest first
  const int q0 = qt * 32;

  const short* Qh = Q + (size_t)bh * SEQ * HD;
  const short* Kh = K + (size_t)bh * SEQ * HD;
  const short* Vh = Vt + (size_t)bh * SEQ * HD;  // [HD][SEQ]

  bf16x8 qf[2][4];
  #pragma unroll
  for (int m = 0; m < 2; ++m)
    #pragma unroll
    for (int c = 0; c < 4; ++c)
      qf[m][c] = *(const bf16x8*)&Qh[(size_t)(q0 + m * 16 + cl) * HD + c * 32 + g * 8];

  f32x4 o[2][8] = {};
  float mrow[2][4], lrow[2][4];
  #pragma unroll
  for (int m = 0; m < 2; ++m)
    #pragma unroll
    for (int r = 0; r < 4; ++r) { mrow[m][r] = -1e30f; lrow[m][r] = 0.f; }

  const float kSc = 0.08838834764831845f * 1.44269504088896341f;  // 1/sqrt(128)*log2e
  const int swzr = (cl & 7) << 4;
  char* Pw = (char*)&Pls[wave][0];
  const int kvlen = q0 + 32;

  for (int j0 = 0; j0 < kvlen; j0 += 64) {
    // ---- QK^T straight from global (L2-served)
    f32x4 s[2][4] = {};
    #pragma unroll
    for (int jf = 0; jf < 4; ++jf) {
      bf16x8 kf[4];
      #pragma unroll
      for (int c = 0; c < 4; ++c)
        kf[c] = *(const bf16x8*)&Kh[(size_t)(j0 + jf * 16 + cl) * HD + c * 32 + g * 8];
      #pragma unroll
      for (int m = 0; m < 2; ++m)
        #pragma unroll
        for (int c = 0; c < 4; ++c)
          s[m][jf] = __builtin_amdgcn_mfma_f32_16x16x32_bf16(qf[m][c], kf[c], s[m][jf], 0, 0, 0);
    }
    // ---- online softmax (exp2 domain), P -> per-wave swizzled LDS
    #pragma unroll
    for (int m = 0; m < 2; ++m) {
      #pragma unroll
      for (int r = 0; r < 4; ++r) {
        const int qi = q0 + m * 16 + g * 4 + r;
        float v[4];
        float mx = -1e30f;
        #pragma unroll
        for (int jf = 0; jf < 4; ++jf) {
          float x = s[m][jf][r] * kSc;
          if (j0 + jf * 16 + cl > qi) x = -1e30f;
          v[jf] = x;
          mx = fmaxf(mx, x);
        }
        #pragma unroll
        for (int off2 = 1; off2 < 16; off2 <<= 1)
          mx = fmaxf(mx, __shfl_xor(mx, off2));
        const float mnew = fmaxf(mrow[m][r], mx);
        const float corr = __builtin_amdgcn_exp2f(mrow[m][r] - mnew);
        mrow[m][r] = mnew;
        const int rl = m * 16 + g * 4 + r;
        const int swzw = (rl & 7) << 4;
        float ps = 0.f;
        #pragma unroll
        for (int jf = 0; jf < 4; ++jf) {
          float p = __builtin_amdgcn_exp2f(v[jf] - mnew);
          ps += p;
          *(short*)(Pw + rl * 128 + (((jf * 16 + cl) * 2) ^ swzw)) = f2bf(p);
        }
        #pragma unroll
        for (int off2 = 1; off2 < 16; off2 <<= 1)
          ps += __shfl_xor(ps, off2);
        lrow[m][r] = lrow[m][r] * corr + ps;
        #pragma unroll
        for (int f = 0; f < 8; ++f) o[m][f][r] *= corr;
      }
    }
    asm volatile("s_waitcnt lgkmcnt(0)" ::: "memory");
    __builtin_amdgcn_sched_barrier(0);  // rule #18: keep MFMA below the wait
    // ---- PV: P from LDS frags, V straight from global (L2-served)
    #pragma unroll
    for (int ks = 0; ks < 2; ++ks) {
      bf16x8 pf[2];
      #pragma unroll
      for (int m = 0; m < 2; ++m)
        pf[m] = *(const bf16x8*)(Pw + (m * 16 + cl) * 128 + ((ks * 64 + g * 16) ^ swzr));
      #pragma unroll
      for (int f = 0; f < 8; ++f) {
        bf16x8 vf = *(const bf16x8*)&Vh[(size_t)(f * 16 + cl) * SEQ + j0 + ks * 32 + g * 8];
        #pragma unroll
        for (int m = 0; m < 2; ++m)
          o[m][f] = __builtin_amdgcn_mfma_f32_16x16x32_bf16(pf[m], vf, o[m][f], 0, 0, 0);
      }
    }
  }

  const int b = bh / NHEADS, h = bh % NHEADS;
  #pragma unroll
  for (int m = 0; m < 2; ++m) {
    #pragma unroll
    for (int r = 0; r < 4; ++r) {
      const int qi = q0 + m * 16 + g * 4 + r;
      const float invl = 1.0f / lrow[m][r];
      size_t base = ((size_t)b * SEQ + qi) * D_EMB + h * HD;
      #pragma unroll
      for (int f = 0; f < 8; ++f)
        O[base + f * 16 + cl] = f2bf(o[m][f][r] * invl);
    }
  }
}

extern "C" void kernel_launch(void* const* d_in, const int* in_sizes, int n_in,
                              void* d_out, int out_size, void* d_ws, size_t ws_size,
                              hipStream_t stream) {
  const float* x  = (const float*)d_in[0];
  const float* Wq = (const float*)d_in[1];
  const float* bq = (const float*)d_in[2];
  const float* Wk = (const float*)d_in[3];
  const float* bk = (const float*)d_in[4];
  const float* Wv = (const float*)d_in[5];
  const float* bv = (const float*)d_in[6];
  const float* Wo = (const float*)d_in[7];
  const float* bo = (const float*)d_in[8];
  float* out = (float*)d_out;

  char* ws = (char*)d_ws;
  size_t off = 0;
  auto carve = [&](size_t bytes) {
    char* p = ws + off;
    off += (bytes + 255) & ~(size_t)255;
    return p;
  };
  short* xb  = (short*)carve((size_t)M_ROWS * D_EMB * 2);
  short* wqt = (short*)carve((size_t)D_EMB * D_EMB * 2);
  short* wkt = (short*)carve((size_t)D_EMB * D_EMB * 2);
  short* wvt = (short*)carve((size_t)D_EMB * D_EMB * 2);
  short* wot = (short*)carve((size_t)D_EMB * D_EMB * 2);
  short* Qb  = (short*)carve((size_t)BH * SEQ * HD * 2);
  short* Kb  = (short*)carve((size_t)BH * SEQ * HD * 2);
  short* Vb  = (short*)carve((size_t)BH * SEQ * HD * 2);
  short* Vtb = (short*)carve((size_t)BH * SEQ * HD * 2);
  short* Ob  = (short*)carve((size_t)M_ROWS * D_EMB * 2);

  int n4 = M_ROWS * D_EMB / 4;
  cvt_f32_bf16_k<<<(n4 + 255) / 256, 256, 0, stream>>>(x, xb, n4);

  dim3 tb(32, 8);
  transpose_w_k<<<dim3(24, 24), tb, 0, stream>>>(Wq, wqt, D_EMB, D_EMB);
  transpose_w_k<<<dim3(24, 24), tb, 0, stream>>>(Wk, wkt, D_EMB, D_EMB);
  transpose_w_k<<<dim3(24, 24), tb, 0, stream>>>(Wv, wvt, D_EMB, D_EMB);
  transpose_w_k<<<dim3(24, 24), tb, 0, stream>>>(Wo, wot, D_EMB, D_EMB);

  dim3 gg(M_ROWS / 128, D_EMB / 64);
  gemm_bt_k<<<gg, 256, 0, stream>>>(xb, wqt, bq, nullptr, Qb, M_ROWS, D_EMB, D_EMB, 1);
  gemm_bt_k<<<gg, 256, 0, stream>>>(xb, wkt, bk, nullptr, Kb, M_ROWS, D_EMB, D_EMB, 1);
  gemm_bt_k<<<gg, 256, 0, stream>>>(xb, wvt, bv, nullptr, Vb, M_ROWS, D_EMB, D_EMB, 1);

  transpose_v_k<<<dim3(HD / 32, SEQ / 32, BH), tb, 0, stream>>>(Vb, Vtb);

  attn_causal_k<<<dim3(384), 256, 0, stream>>>(Qb, Kb, Vtb, Ob);

  gemm_bt_k<<<gg, 256, 0, stream>>>(Ob, wot, bo, out, nullptr, M_ROWS, D_EMB, D_EMB, 0);
}